// Round 1
// 134.386 us; speedup vs baseline: 1.0659x; 1.0659x over previous
//
#include <hip/hip_runtime.h>

// Problem constants
#define BATCH 64
#define NNODE 1024
#define FDIM  200
#define MROWS (BATCH * NNODE)   // 65536
#define NEG_SLOPE 0.2f

#define NKT 7                   // k-tiles of 32 for W-GEMM (K 200 -> 224)
#define NNT 13                  // n-tiles of 16 (N 200 -> 208)
#define KTBYTES (NNT * 1024)    // 13312 B: one kt-tile of B fragments
#define KSPLIT 4                // j-split for k_attn

typedef short s16x8 __attribute__((ext_vector_type(8)));
typedef float f32x4 __attribute__((ext_vector_type(4)));

// ws layout (bytes):
//   h0frag : bf16 B-fragments of h0, 32 kt2 x 13 nt x 1024 B   [0, 425984)
//   a_s    : float[1024]  @ 425984
//   a_d    : float[1024]  @ 430080
//   m_i    : float[1024]  @ 434176
//   l_i    : float[1024]  @ 438272
//   fragW  : bf16 B-fragments of W, 7 kt x 13 nt x 1024 B @ 442368 (93,184 B)
//   wsv    : float[200] @ 535552   (W @ att_src)
//   wdv    : float[200] @ 536352   (W @ att_dst)

__device__ __forceinline__ unsigned int f2bf(float f) {
    unsigned int u = __float_as_uint(f);
    return (u + 0x7fffu + ((u >> 16) & 1u)) >> 16;
}
__device__ __forceinline__ unsigned int pack2(float a, float b) {
    return f2bf(a) | (f2bf(b) << 16);
}

// ---------------------------------------------------------------------------
// k_prep: blocks 0..90  : W -> bf16 B-fragments (16x16x32 layout), 224x208 pad
//         blocks 91..290: wsv[k]/wdv[k] = dot(W[k,:], att_src/att_dst)
// ---------------------------------------------------------------------------
__global__ __launch_bounds__(64) void k_prep(const float* __restrict__ W,
                                             const float* __restrict__ att_src,
                                             const float* __restrict__ att_dst,
                                             unsigned short* __restrict__ fragW,
                                             float* __restrict__ wsv,
                                             float* __restrict__ wdv)
{
    const int b    = blockIdx.x;
    const int lane = threadIdx.x;

    if (b < 91) {
        const int kt   = b / NNT;
        const int nt   = b - kt * NNT;
        const int n    = nt * 16 + (lane & 15);
        const int kb   = kt * 32 + (lane >> 4) * 8;
        s16x8 v;
        #pragma unroll
        for (int j = 0; j < 8; ++j) {
            int k = kb + j;
            float f = (k < FDIM && n < FDIM) ? W[k * FDIM + n] : 0.f;
            v[j] = (short)f2bf(f);
        }
        ((s16x8*)(fragW + (size_t)b * 512))[lane] = v;
    } else {
        const int kk = b - 91;               // [0, 200)
        const float* Wr = W + kk * FDIM;
        float ps = 0.f, pd = 0.f;
        #pragma unroll
        for (int i = 0; i < 4; ++i) {
            int n = lane + i * 64;
            if (n < FDIM) {
                float wv = Wr[n];
                ps = fmaf(wv, att_src[n], ps);
                pd = fmaf(wv, att_dst[n], pd);
            }
        }
        #pragma unroll
        for (int off = 32; off; off >>= 1) {
            ps += __shfl_down(ps, off);
            pd += __shfl_down(pd, off);
        }
        if (lane == 0) { wsv[kk] = ps; wdv[kk] = pd; }
    }
}

// ---------------------------------------------------------------------------
// k_av: a_s = x0 @ wsv, a_d = x0 @ wdv  (reassociated (x@W)@att = x@(W@att)).
// ---------------------------------------------------------------------------
__global__ __launch_bounds__(256) void k_av(const float* __restrict__ x,
                                            const float* __restrict__ wsv,
                                            const float* __restrict__ wdv,
                                            float* __restrict__ a_s,
                                            float* __restrict__ a_d)
{
    const int tid  = threadIdx.x;
    const int lane = tid & 63;
    const int row  = blockIdx.x * 4 + (tid >> 6);
    const float* xr = x + (size_t)row * FDIM;
    float ss = 0.f, sd = 0.f;
    for (int k = lane; k < FDIM; k += 64) {
        float xv = xr[k];
        ss = fmaf(xv, wsv[k], ss);
        sd = fmaf(xv, wdv[k], sd);
    }
    #pragma unroll
    for (int off = 32; off; off >>= 1) {
        ss += __shfl_down(ss, off);
        sd += __shfl_down(sd, off);
    }
    if (lane == 0) { a_s[row] = ss; a_d[row] = sd; }
}

// ---------------------------------------------------------------------------
// k_gemm: h = x @ W. 1024 blocks x 256 thr (4 waves x 16 rows = 64 rows).
// B (fragW) staged per-kt into LDS (double-buffered) via global_load_lds and
// shared by all 4 waves: 4x less L2 B-traffic than 1-wave blocks, ~12 waves/CU.
//   R0 >= 1024: out = h + bias.
//   R0 <  1024: h -> h0frag (bf16 B-layout via LDS transpose, Bs reused) only.
// ---------------------------------------------------------------------------
__global__ __launch_bounds__(256) void k_gemm(const float* __restrict__ x,
                                              const unsigned short* __restrict__ fragW,
                                              const float* __restrict__ bias,
                                              float* __restrict__ out,
                                              unsigned short* __restrict__ h0frag)
{
    __shared__ __align__(16) unsigned short Bs[2][KTBYTES / 2];   // 26,624 B
    const int tid  = threadIdx.x;
    const int lane = tid & 63;
    const int w    = __builtin_amdgcn_readfirstlane(tid >> 6);
    const int ln   = lane & 15;
    const int quad = lane >> 4;
    const int R0   = blockIdx.x * 64;
    const int row0 = R0 + w * 16;

    // stage one kt-tile (13,312 B) of fragW into Bs[buf_]; wave w covers
    // fragment groups g = {w, w+4, w+8, w+12} (g<13), 64 lanes x 16 B each.
#define STAGE(kt_, buf_)                                                      \
    {                                                                         \
        const char* gsrc = (const char*)fragW + (size_t)(kt_) * KTBYTES;      \
        char* lbase = (char*)&Bs[buf_][0];                                    \
        _Pragma("unroll")                                                     \
        for (int i = 0; i < 4; ++i) {                                         \
            int g = i * 4 + w;                                                \
            if (g < NNT)                                                      \
                __builtin_amdgcn_global_load_lds(                             \
                    (const __attribute__((address_space(1))) void*)           \
                        (gsrc + g * 1024 + lane * 16),                        \
                    (__attribute__((address_space(3))) void*)                 \
                        (lbase + g * 1024),                                   \
                    16, 0, 0);                                                \
        }                                                                     \
    }

    f32x4 acc[NNT];
    #pragma unroll
    for (int nt = 0; nt < NNT; ++nt) acc[nt] = (f32x4){0.f, 0.f, 0.f, 0.f};

    const float* xrow = x + (size_t)(row0 + ln) * FDIM;

    // rolling A prefetch (raw fp32), 4 deep
    float4 ar[NKT][2];
    #pragma unroll
    for (int kt = 0; kt < 4; ++kt) {
        const float4* ap = (const float4*)(xrow + kt * 32 + quad * 8);
        ar[kt][0] = ap[0]; ar[kt][1] = ap[1];
    }

    STAGE(0, 0);
    __syncthreads();

    #pragma unroll
    for (int kt = 0; kt < NKT; ++kt) {
        const int cur = kt & 1;
        if (kt < NKT - 1) STAGE(kt + 1, cur ^ 1);

        // prefetch A 4 ahead
        if (kt + 4 < NKT) {
            int ka = kt + 4;
            if (ka < 6) {
                const float4* ap = (const float4*)(xrow + ka * 32 + quad * 8);
                ar[ka][0] = ap[0]; ar[ka][1] = ap[1];
            } else {                      // ka==6: only quad 0 in-bounds
                if (quad == 0) {
                    const float4* ap = (const float4*)(xrow + ka * 32);
                    ar[ka][0] = ap[0]; ar[ka][1] = ap[1];
                } else {
                    ar[ka][0] = make_float4(0.f, 0.f, 0.f, 0.f);
                    ar[ka][1] = make_float4(0.f, 0.f, 0.f, 0.f);
                }
            }
        }
        // pack current A frag
        float4 f0 = ar[kt][0], f1 = ar[kt][1];
        unsigned int au[4] = {pack2(f0.x, f0.y), pack2(f0.z, f0.w),
                              pack2(f1.x, f1.y), pack2(f1.z, f1.w)};
        s16x8 a = *(s16x8*)au;

        const unsigned short* bbase = &Bs[cur][0];
        #pragma unroll
        for (int nt = 0; nt < NNT; ++nt) {
            s16x8 b = *(const s16x8*)(bbase + nt * 512 + lane * 8);
            acc[nt] = __builtin_amdgcn_mfma_f32_16x16x32_bf16(a, b, acc[nt], 0, 0, 0);
        }
        if (kt < NKT - 1) __syncthreads();
    }
#undef STAGE

    // D layout: col = nt*16 + ln, row = quad*4 + r
    if (R0 >= NNODE) {
        #pragma unroll
        for (int nt = 0; nt < NNT; ++nt) {
            int col = nt * 16 + ln;
            if (nt < 12 || ln < 8) {
                float bv = bias[col];
                #pragma unroll
                for (int r = 0; r < 4; ++r)
                    out[(size_t)(row0 + quad * 4 + r) * FDIM + col] = acc[nt][r] + bv;
            }
        }
    } else {
        // h0frag: transpose C-layout -> bf16 B-fragment halves.
        // Reuse Bs as per-wave transpose scratch (16x17 floats per wave).
        __syncthreads();                       // all waves done reading Bs
        float* scrw = (float*)&Bs[0][0] + w * (16 * 17);
        const int kt2 = row0 >> 5;
        const int lo  = (row0 >> 4) & 1;
        for (int nt = 0; nt < NNT; ++nt) {
            #pragma unroll
            for (int r = 0; r < 4; ++r) scrw[(quad * 4 + r) * 17 + ln] = acc[nt][r];
            __syncthreads();
            if (lane < 32) {                   // half-frag: lane = oct*16 + n
                int oct = lane >> 4, nl = lane & 15;
                uint4 dv;
                dv.x = pack2(scrw[(oct * 8 + 0) * 17 + nl], scrw[(oct * 8 + 1) * 17 + nl]);
                dv.y = pack2(scrw[(oct * 8 + 2) * 17 + nl], scrw[(oct * 8 + 3) * 17 + nl]);
                dv.z = pack2(scrw[(oct * 8 + 4) * 17 + nl], scrw[(oct * 8 + 5) * 17 + nl]);
                dv.w = pack2(scrw[(oct * 8 + 6) * 17 + nl], scrw[(oct * 8 + 7) * 17 + nl]);
                *(uint4*)(h0frag + ((size_t)(kt2 * NNT + nt) * 64 + lo * 32 + lane) * 8) = dv;
            }
            __syncthreads();
        }
    }
}

// ---------------------------------------------------------------------------
// k_stats: per-row softmax stats + init out[0:1024] = bias (k_attn atomicAdds
// the alpha@h0 partials on top).
// ---------------------------------------------------------------------------
__global__ __launch_bounds__(256) void k_stats(const float* __restrict__ a_s,
                                               const float* __restrict__ a_d,
                                               const float* __restrict__ bias,
                                               float* __restrict__ out,
                                               float* __restrict__ m_out,
                                               float* __restrict__ l_out)
{
    __shared__ float as_s[1024];
    const int tid = threadIdx.x;

    // bias init for the 4 out0 rows this block owns
    if (tid < FDIM) {
        float bv = bias[tid];
        #pragma unroll
        for (int r = 0; r < 4; ++r)
            out[(size_t)(blockIdx.x * 4 + r) * FDIM + tid] = bv;
    }

    #pragma unroll
    for (int i = 0; i < 4; ++i) as_s[tid + i * 256] = a_s[tid + i * 256];
    __syncthreads();

    const int lane = tid & 63;
    const int row  = blockIdx.x * 4 + (tid >> 6);

    float mx = -1e30f;
    #pragma unroll
    for (int i = 0; i < 16; ++i) mx = fmaxf(mx, as_s[lane + i * 64]);
    #pragma unroll
    for (int off = 32; off; off >>= 1) mx = fmaxf(mx, __shfl_down(mx, off));
    mx = __shfl(mx, 0);

    const float ad = a_d[row];
    float mi = ad + mx; mi = (mi > 0.f) ? mi : NEG_SLOPE * mi;

    float sum = 0.f;
    #pragma unroll
    for (int i = 0; i < 16; ++i) {
        float s = ad + as_s[lane + i * 64];
        s = (s > 0.f) ? s : NEG_SLOPE * s;
        sum += __expf(s - mi);
    }
    #pragma unroll
    for (int off = 32; off; off >>= 1) sum += __shfl_down(sum, off);
    if (lane == 0) { m_out[row] = mi; l_out[row] = sum; }
}

// ---------------------------------------------------------------------------
// k_attn: out0 += (alpha @ h0) / l  via MFMA, 4-way j-split with atomicAdd.
// 832 blocks = KSPLIT x 16 it x 13 nt; 4 waves/block, wave = 16 i-rows,
// 8 kt2 (256 j) per block. Softmax stats are global so partials just add.
// ---------------------------------------------------------------------------
__global__ __launch_bounds__(256) void k_attn(const unsigned short* __restrict__ h0frag,
                                              const float* __restrict__ a_s,
                                              const float* __restrict__ a_d,
                                              const float* __restrict__ m_v,
                                              const float* __restrict__ l_v,
                                              float* __restrict__ out)
{
    const int tid  = threadIdx.x;
    const int lane = tid & 63;
    const int w    = __builtin_amdgcn_readfirstlane(tid >> 6);
    const int ln   = lane & 15;
    const int quad = lane >> 4;
    const int bid  = blockIdx.x;
    const int kh   = bid / (16 * NNT);          // 0..3
    const int r2   = bid - kh * (16 * NNT);
    const int it   = r2 / NNT;
    const int nt   = r2 - it * NNT;
    const int i0   = it * 64 + w * 16;

    const float ad = a_d[i0 + ln];
    const float mi = m_v[i0 + ln];

    f32x4 accA = (f32x4){0.f, 0.f, 0.f, 0.f};
    f32x4 accB = (f32x4){0.f, 0.f, 0.f, 0.f};

    #pragma unroll
    for (int k8 = 0; k8 < 8; ++k8) {
        const int kt2 = kh * 8 + k8;
        const float4* ap = (const float4*)(a_s + kt2 * 32 + quad * 8);
        float4 f0 = ap[0], f1 = ap[1];
        float e[8] = {f0.x, f0.y, f0.z, f0.w, f1.x, f1.y, f1.z, f1.w};
        #pragma unroll
        for (int j = 0; j < 8; ++j) {
            float s = ad + e[j];
            s = (s > 0.f) ? s : NEG_SLOPE * s;
            e[j] = __expf(s - mi);
        }
        unsigned int au[4] = {pack2(e[0], e[1]), pack2(e[2], e[3]),
                              pack2(e[4], e[5]), pack2(e[6], e[7])};
        s16x8 afrag = *(s16x8*)au;
        s16x8 b = *(const s16x8*)(h0frag + ((size_t)(kt2 * NNT + nt) * 64 + lane) * 8);
        if (k8 & 1) accB = __builtin_amdgcn_mfma_f32_16x16x32_bf16(afrag, b, accB, 0, 0, 0);
        else        accA = __builtin_amdgcn_mfma_f32_16x16x32_bf16(afrag, b, accA, 0, 0, 0);
    }

    const int col = nt * 16 + ln;
    if (nt < 12 || ln < 8) {
        #pragma unroll
        for (int r = 0; r < 4; ++r) {
            float rl = 1.0f / l_v[i0 + quad * 4 + r];
            atomicAdd(&out[(size_t)(i0 + quad * 4 + r) * FDIM + col],
                      (accA[r] + accB[r]) * rl);
        }
    }
}

// ---------------------------------------------------------------------------
extern "C" void kernel_launch(void* const* d_in, const int* in_sizes, int n_in,
                              void* d_out, int out_size, void* d_ws, size_t ws_size,
                              hipStream_t stream)
{
    const float* x       = (const float*)d_in[0];
    const float* W       = (const float*)d_in[1];
    const float* att_src = (const float*)d_in[2];
    const float* att_dst = (const float*)d_in[3];
    const float* bias    = (const float*)d_in[4];
    float* out = (float*)d_out;
    char*  wsb = (char*)d_ws;

    unsigned short* h0frag = (unsigned short*)(wsb + 0);       // 425,984 B
    float* a_s   = (float*)(wsb + 425984);
    float* a_d   = (float*)(wsb + 430080);
    float* m_i   = (float*)(wsb + 434176);
    float* l_i   = (float*)(wsb + 438272);
    unsigned short* fragW = (unsigned short*)(wsb + 442368);   // 93,184 B
    float* wsv   = (float*)(wsb + 535552);
    float* wdv   = (float*)(wsb + 536352);

    k_prep <<<291,           64, 0, stream>>>(W, att_src, att_dst, fragW, wsv, wdv);
    k_av   <<<NNODE / 4,    256, 0, stream>>>(x, wsv, wdv, a_s, a_d);
    k_stats<<<NNODE / 4,    256, 0, stream>>>(a_s, a_d, bias, out, m_i, l_i);
    k_gemm <<<MROWS / 64,   256, 0, stream>>>(x, fragW, bias, out, h0frag);
    k_attn <<<KSPLIT * 16 * NNT, 256, 0, stream>>>(h0frag, a_s, a_d, m_i, l_i, out);
}

// Round 2
// 132.036 us; speedup vs baseline: 1.0848x; 1.0178x over previous
//
#include <hip/hip_runtime.h>

// Problem constants
#define BATCH 64
#define NNODE 1024
#define FDIM  200
#define MROWS (BATCH * NNODE)   // 65536
#define NEG_SLOPE 0.2f

#define NKT 7                   // k-tiles of 32 for W-GEMM (K 200 -> 224)
#define NNT 13                  // n-tiles of 16 (N 200 -> 208)
#define KTBYTES (NNT * 1024)    // 13312 B: one kt-tile of B fragments

typedef short s16x8 __attribute__((ext_vector_type(8)));
typedef float f32x4 __attribute__((ext_vector_type(4)));

// ws layout (bytes):
//   h0frag : bf16 B-fragments of h0, 32 kt2 x 13 nt x 1024 B   [0, 425984)
//   a_s    : float[1024]  @ 425984
//   a_d    : float[1024]  @ 430080
//   m_i    : float[1024]  @ 434176
//   l_i    : float[1024]  @ 438272
//   fragW  : bf16 B-fragments of W, 7 kt x 13 nt x 1024 B @ 442368 (93,184 B)
//   wsv    : float[200] @ 535552   (W @ att_src)
//   wdv    : float[200] @ 536352   (W @ att_dst)

__device__ __forceinline__ unsigned int f2bf(float f) {
    unsigned int u = __float_as_uint(f);
    return (u + 0x7fffu + ((u >> 16) & 1u)) >> 16;
}
__device__ __forceinline__ unsigned int pack2(float a, float b) {
    return f2bf(a) | (f2bf(b) << 16);
}

// ---------------------------------------------------------------------------
// k_prep: blocks 0..90  : W -> bf16 B-fragments (16x16x32 layout), 224x208 pad
//         blocks 91..290: wsv[k]/wdv[k] = dot(W[k,:], att_src/att_dst)
// ---------------------------------------------------------------------------
__global__ __launch_bounds__(64) void k_prep(const float* __restrict__ W,
                                             const float* __restrict__ att_src,
                                             const float* __restrict__ att_dst,
                                             unsigned short* __restrict__ fragW,
                                             float* __restrict__ wsv,
                                             float* __restrict__ wdv)
{
    const int b    = blockIdx.x;
    const int lane = threadIdx.x;

    if (b < 91) {
        const int kt   = b / NNT;
        const int nt   = b - kt * NNT;
        const int n    = nt * 16 + (lane & 15);
        const int kb   = kt * 32 + (lane >> 4) * 8;
        s16x8 v;
        #pragma unroll
        for (int j = 0; j < 8; ++j) {
            int k = kb + j;
            float f = (k < FDIM && n < FDIM) ? W[k * FDIM + n] : 0.f;
            v[j] = (short)f2bf(f);
        }
        ((s16x8*)(fragW + (size_t)b * 512))[lane] = v;
    } else {
        const int kk = b - 91;               // [0, 200)
        const float* Wr = W + kk * FDIM;
        float ps = 0.f, pd = 0.f;
        #pragma unroll
        for (int i = 0; i < 4; ++i) {
            int n = lane + i * 64;
            if (n < FDIM) {
                float wv = Wr[n];
                ps = fmaf(wv, att_src[n], ps);
                pd = fmaf(wv, att_dst[n], pd);
            }
        }
        #pragma unroll
        for (int off = 32; off; off >>= 1) {
            ps += __shfl_down(ps, off);
            pd += __shfl_down(pd, off);
        }
        if (lane == 0) { wsv[kk] = ps; wdv[kk] = pd; }
    }
}

// ---------------------------------------------------------------------------
// k_av: a_s = x0 @ wsv, a_d = x0 @ wdv  (reassociated (x@W)@att = x@(W@att)).
// ---------------------------------------------------------------------------
__global__ __launch_bounds__(256) void k_av(const float* __restrict__ x,
                                            const float* __restrict__ wsv,
                                            const float* __restrict__ wdv,
                                            float* __restrict__ a_s,
                                            float* __restrict__ a_d)
{
    const int tid  = threadIdx.x;
    const int lane = tid & 63;
    const int row  = blockIdx.x * 4 + (tid >> 6);
    const float* xr = x + (size_t)row * FDIM;
    float ss = 0.f, sd = 0.f;
    for (int k = lane; k < FDIM; k += 64) {
        float xv = xr[k];
        ss = fmaf(xv, wsv[k], ss);
        sd = fmaf(xv, wdv[k], sd);
    }
    #pragma unroll
    for (int off = 32; off; off >>= 1) {
        ss += __shfl_down(ss, off);
        sd += __shfl_down(sd, off);
    }
    if (lane == 0) { a_s[row] = ss; a_d[row] = sd; }
}

// ---------------------------------------------------------------------------
// k_gemm: h = x @ W. 1024 blocks x 256 thr (4 waves x 16 rows = 64 rows).
// BK=64 phases: 4 barrier phases (26 MFMAs each) instead of 7 (13 each),
// double-buffered 2-kt LDS stages via global_load_lds. A is a 2-phase rolling
// register prefetch (32 VGPRs) to stay under the 128-VGPR occupancy cliff
// (__launch_bounds__(256,4) -> 4 blocks/CU, 16 waves/CU).
//   R0 >= 1024: out = h + bias.
//   R0 <  1024: h -> h0frag (bf16 B-layout via LDS transpose, Bs reused) only.
// ---------------------------------------------------------------------------
__global__ __launch_bounds__(256, 4) void k_gemm(const float* __restrict__ x,
                                                 const unsigned short* __restrict__ fragW,
                                                 const float* __restrict__ bias,
                                                 float* __restrict__ out,
                                                 unsigned short* __restrict__ h0frag)
{
    __shared__ __align__(16) unsigned short Bs[2][2 * KTBYTES / 2]; // 53,248 B
    const int tid  = threadIdx.x;
    const int lane = tid & 63;
    const int w    = __builtin_amdgcn_readfirstlane(tid >> 6);
    const int ln   = lane & 15;
    const int quad = lane >> 4;
    const int R0   = blockIdx.x * 64;
    const int row0 = R0 + w * 16;

    // stage ntile_ kt-tiles (13,312 B each) starting at kt0_ into Bs[buf_];
    // groups of 1024 B, wave w covers g = i*4+w, 64 lanes x 16 B each.
#define STAGE(kt0_, ntile_, buf_)                                             \
    {                                                                         \
        const char* gsrc = (const char*)fragW + (size_t)(kt0_) * KTBYTES;     \
        char* lbase = (char*)&Bs[buf_][0];                                    \
        const int ngroups = (ntile_) * NNT;                                   \
        _Pragma("unroll")                                                     \
        for (int i = 0; i < 7; ++i) {                                         \
            int g = i * 4 + w;                                                \
            if (g < ngroups)                                                  \
                __builtin_amdgcn_global_load_lds(                             \
                    (const __attribute__((address_space(1))) void*)           \
                        (gsrc + g * 1024 + lane * 16),                        \
                    (__attribute__((address_space(3))) void*)                 \
                        (lbase + g * 1024),                                   \
                    16, 0, 0);                                                \
        }                                                                     \
    }

    // load A for phase p_ (kt = 2p_, 2p_+1) into ar[slot_]
#define LOADA(p_, slot_)                                                      \
    {                                                                         \
        const int kt0_ = 2 * (p_);                                            \
        if (kt0_ < 6) {                                                       \
            const float4* ap = (const float4*)(xrow + kt0_ * 32 + quad * 8);  \
            ar[slot_][0][0] = ap[0]; ar[slot_][0][1] = ap[1];                 \
        } else {                                                              \
            if (quad == 0) {                                                  \
                const float4* ap = (const float4*)(xrow + kt0_ * 32);         \
                ar[slot_][0][0] = ap[0]; ar[slot_][0][1] = ap[1];             \
            } else {                                                          \
                ar[slot_][0][0] = make_float4(0.f, 0.f, 0.f, 0.f);            \
                ar[slot_][0][1] = make_float4(0.f, 0.f, 0.f, 0.f);            \
            }                                                                 \
        }                                                                     \
        if (kt0_ + 1 < NKT) {                                                 \
            const float4* ap = (const float4*)(xrow + (kt0_ + 1) * 32 + quad * 8); \
            ar[slot_][1][0] = ap[0]; ar[slot_][1][1] = ap[1];                 \
        }                                                                     \
    }

    f32x4 acc[NNT];
    #pragma unroll
    for (int nt = 0; nt < NNT; ++nt) acc[nt] = (f32x4){0.f, 0.f, 0.f, 0.f};

    const float* xrow = x + (size_t)(row0 + ln) * FDIM;
    float4 ar[2][2][2];                 // [slot][kt-in-phase][half]

    LOADA(0, 0);
    STAGE(0, 2, 0);
    __syncthreads();

    #pragma unroll
    for (int p = 0; p < 4; ++p) {
        const int cur = p & 1;
        if (p < 3) {
            STAGE(2 * (p + 1), ((p < 2) ? 2 : 1), cur ^ 1);
            LOADA(p + 1, cur ^ 1);
        }
        // first kt of phase
        {
            float4 f0 = ar[cur][0][0], f1 = ar[cur][0][1];
            unsigned int au[4] = {pack2(f0.x, f0.y), pack2(f0.z, f0.w),
                                  pack2(f1.x, f1.y), pack2(f1.z, f1.w)};
            s16x8 a = *(s16x8*)au;
            const unsigned short* bbase = &Bs[cur][0];
            #pragma unroll
            for (int nt = 0; nt < NNT; ++nt) {
                s16x8 b = *(const s16x8*)(bbase + nt * 512 + lane * 8);
                acc[nt] = __builtin_amdgcn_mfma_f32_16x16x32_bf16(a, b, acc[nt], 0, 0, 0);
            }
        }
        // second kt of phase (phases 0..2 only)
        if (p < 3) {
            float4 f0 = ar[cur][1][0], f1 = ar[cur][1][1];
            unsigned int au[4] = {pack2(f0.x, f0.y), pack2(f0.z, f0.w),
                                  pack2(f1.x, f1.y), pack2(f1.z, f1.w)};
            s16x8 a = *(s16x8*)au;
            const unsigned short* bbase = &Bs[cur][0] + (KTBYTES / 2);
            #pragma unroll
            for (int nt = 0; nt < NNT; ++nt) {
                s16x8 b = *(const s16x8*)(bbase + nt * 512 + lane * 8);
                acc[nt] = __builtin_amdgcn_mfma_f32_16x16x32_bf16(a, b, acc[nt], 0, 0, 0);
            }
        }
        __syncthreads();
    }
#undef STAGE
#undef LOADA

    // D layout: col = nt*16 + ln, row = quad*4 + r
    if (R0 >= NNODE) {
        #pragma unroll
        for (int nt = 0; nt < NNT; ++nt) {
            int col = nt * 16 + ln;
            if (nt < 12 || ln < 8) {
                float bv = bias[col];
                #pragma unroll
                for (int r = 0; r < 4; ++r)
                    out[(size_t)(row0 + quad * 4 + r) * FDIM + col] = acc[nt][r] + bv;
            }
        }
    } else {
        // h0frag: transpose C-layout -> bf16 B-fragment halves.
        // Reuse Bs as per-wave transpose scratch (16x17 floats per wave).
        float* scrw = (float*)&Bs[0][0] + w * (16 * 17);
        const int kt2 = row0 >> 5;
        const int lo  = (row0 >> 4) & 1;
        for (int nt = 0; nt < NNT; ++nt) {
            #pragma unroll
            for (int r = 0; r < 4; ++r) scrw[(quad * 4 + r) * 17 + ln] = acc[nt][r];
            __syncthreads();
            if (lane < 32) {                   // half-frag: lane = oct*16 + n
                int oct = lane >> 4, nl = lane & 15;
                uint4 dv;
                dv.x = pack2(scrw[(oct * 8 + 0) * 17 + nl], scrw[(oct * 8 + 1) * 17 + nl]);
                dv.y = pack2(scrw[(oct * 8 + 2) * 17 + nl], scrw[(oct * 8 + 3) * 17 + nl]);
                dv.z = pack2(scrw[(oct * 8 + 4) * 17 + nl], scrw[(oct * 8 + 5) * 17 + nl]);
                dv.w = pack2(scrw[(oct * 8 + 6) * 17 + nl], scrw[(oct * 8 + 7) * 17 + nl]);
                *(uint4*)(h0frag + ((size_t)(kt2 * NNT + nt) * 64 + lo * 32 + lane) * 8) = dv;
            }
            __syncthreads();
        }
    }
}

// ---------------------------------------------------------------------------
// k_stats: per-row softmax stats. lrelu monotone => row max = lrelu(ad + max a_s).
// ---------------------------------------------------------------------------
__global__ __launch_bounds__(256) void k_stats(const float* __restrict__ a_s,
                                               const float* __restrict__ a_d,
                                               float* __restrict__ m_out,
                                               float* __restrict__ l_out)
{
    __shared__ float as_s[1024];
    const int tid = threadIdx.x;
    #pragma unroll
    for (int i = 0; i < 4; ++i) as_s[tid + i * 256] = a_s[tid + i * 256];
    __syncthreads();

    const int lane = tid & 63;
    const int row  = blockIdx.x * 4 + (tid >> 6);

    float mx = -1e30f;
    #pragma unroll
    for (int i = 0; i < 16; ++i) mx = fmaxf(mx, as_s[lane + i * 64]);
    #pragma unroll
    for (int off = 32; off; off >>= 1) mx = fmaxf(mx, __shfl_down(mx, off));
    mx = __shfl(mx, 0);

    const float ad = a_d[row];
    float mi = ad + mx; mi = (mi > 0.f) ? mi : NEG_SLOPE * mi;

    float sum = 0.f;
    #pragma unroll
    for (int i = 0; i < 16; ++i) {
        float s = ad + as_s[lane + i * 64];
        s = (s > 0.f) ? s : NEG_SLOPE * s;
        sum += __expf(s - mi);
    }
    #pragma unroll
    for (int off = 32; off; off >>= 1) sum += __shfl_down(sum, off);
    if (lane == 0) { m_out[row] = sum, m_out[row] = mi, l_out[row] = sum; }
}

// ---------------------------------------------------------------------------
// k_attn: out0 = (alpha @ h0) + bias via MFMA. NO atomics: j-split across the
// 4 waves of a block (8 kt2 each), cross-wave LDS reduce, wave 0 stores.
// 832 blocks = 64 i-tiles (16 rows) x 13 nt.
// ---------------------------------------------------------------------------
__global__ __launch_bounds__(256) void k_attn(const unsigned short* __restrict__ h0frag,
                                              const float* __restrict__ a_s,
                                              const float* __restrict__ a_d,
                                              const float* __restrict__ m_v,
                                              const float* __restrict__ l_v,
                                              const float* __restrict__ bias,
                                              float* __restrict__ out)
{
    __shared__ f32x4 red[3][64];
    const int tid  = threadIdx.x;
    const int lane = tid & 63;
    const int w    = __builtin_amdgcn_readfirstlane(tid >> 6);
    const int ln   = lane & 15;
    const int quad = lane >> 4;
    const int it   = blockIdx.x / NNT;          // 0..63 (16-row i-tiles)
    const int nt   = blockIdx.x - it * NNT;
    const int i0   = it * 16;

    const float ad = a_d[i0 + ln];
    const float mi = m_v[i0 + ln];

    f32x4 accA = (f32x4){0.f, 0.f, 0.f, 0.f};
    f32x4 accB = (f32x4){0.f, 0.f, 0.f, 0.f};

    #pragma unroll
    for (int k8 = 0; k8 < 8; ++k8) {
        const int kt2 = w * 8 + k8;             // wave's j-quarter
        const float4* ap = (const float4*)(a_s + kt2 * 32 + quad * 8);
        float4 f0 = ap[0], f1 = ap[1];
        float e[8] = {f0.x, f0.y, f0.z, f0.w, f1.x, f1.y, f1.z, f1.w};
        #pragma unroll
        for (int j = 0; j < 8; ++j) {
            float s = ad + e[j];
            s = (s > 0.f) ? s : NEG_SLOPE * s;
            e[j] = __expf(s - mi);
        }
        unsigned int au[4] = {pack2(e[0], e[1]), pack2(e[2], e[3]),
                              pack2(e[4], e[5]), pack2(e[6], e[7])};
        s16x8 afrag = *(s16x8*)au;
        s16x8 b = *(const s16x8*)(h0frag + ((size_t)(kt2 * NNT + nt) * 64 + lane) * 8);
        if (k8 & 1) accB = __builtin_amdgcn_mfma_f32_16x16x32_bf16(afrag, b, accB, 0, 0, 0);
        else        accA = __builtin_amdgcn_mfma_f32_16x16x32_bf16(afrag, b, accA, 0, 0, 0);
    }

    f32x4 acc = accA + accB;
    if (w > 0) red[w - 1][lane] = acc;
    __syncthreads();

    if (w == 0) {
        #pragma unroll
        for (int ww = 0; ww < 3; ++ww) acc += red[ww][lane];
        const int col = nt * 16 + ln;
        if (nt < 12 || ln < 8) {
            float bv = bias[col];
            #pragma unroll
            for (int r = 0; r < 4; ++r) {
                float rl = 1.0f / l_v[i0 + quad * 4 + r];
                out[(size_t)(i0 + quad * 4 + r) * FDIM + col] = acc[r] * rl + bv;
            }
        }
    }
}

// ---------------------------------------------------------------------------
extern "C" void kernel_launch(void* const* d_in, const int* in_sizes, int n_in,
                              void* d_out, int out_size, void* d_ws, size_t ws_size,
                              hipStream_t stream)
{
    const float* x       = (const float*)d_in[0];
    const float* W       = (const float*)d_in[1];
    const float* att_src = (const float*)d_in[2];
    const float* att_dst = (const float*)d_in[3];
    const float* bias    = (const float*)d_in[4];
    float* out = (float*)d_out;
    char*  wsb = (char*)d_ws;

    unsigned short* h0frag = (unsigned short*)(wsb + 0);       // 425,984 B
    float* a_s   = (float*)(wsb + 425984);
    float* a_d   = (float*)(wsb + 430080);
    float* m_i   = (float*)(wsb + 434176);
    float* l_i   = (float*)(wsb + 438272);
    unsigned short* fragW = (unsigned short*)(wsb + 442368);   // 93,184 B
    float* wsv   = (float*)(wsb + 535552);
    float* wdv   = (float*)(wsb + 536352);

    k_prep <<<291,         64, 0, stream>>>(W, att_src, att_dst, fragW, wsv, wdv);
    k_av   <<<NNODE / 4,  256, 0, stream>>>(x, wsv, wdv, a_s, a_d);
    k_stats<<<NNODE / 4,  256, 0, stream>>>(a_s, a_d, m_i, l_i);
    k_gemm <<<MROWS / 64, 256, 0, stream>>>(x, fragW, bias, out, h0frag);
    k_attn <<<64 * NNT,   256, 0, stream>>>(h0frag, a_s, a_d, m_i, l_i, bias, out);
}